// Round 1
// 319.395 us; speedup vs baseline: 1.0587x; 1.0587x over previous
//
#include <hip/hip_runtime.h>
#include <hip/hip_bf16.h>

#define NN 4096
#define DD 256
#define BB 32
#define TT 256
#define EPS 1e-6f
#define DECAY 0.97f
#define LOG2_DECAY -0.043943348f

typedef __hip_bfloat16 bf16;
typedef short short8 __attribute__((ext_vector_type(8)));
typedef float floatx4 __attribute__((ext_vector_type(4)));

__device__ __forceinline__ float bfu2f(short u) {
    return __uint_as_float(((unsigned)(unsigned short)u) << 16);
}

// ---------------- block-wide sum over 256 threads ----------------
__device__ __forceinline__ float blk_sum_256(float v, volatile float* s4) {
#pragma unroll
    for (int o = 32; o > 0; o >>= 1) v += __shfl_down(v, o, 64);
    int lane = threadIdx.x & 63, w = threadIdx.x >> 6;
    __syncthreads();
    if (lane == 0) s4[w] = v;
    __syncthreads();
    return s4[0] + s4[1] + s4[2] + s4[3];
}

// async global->LDS, 16B per lane; LDS dest must be wave-uniform base + lane*16
__device__ __forceinline__ void gl16(const bf16* g, bf16* l) {
    __builtin_amdgcn_global_load_lds((const __attribute__((address_space(1))) void*)g,
                                     (__attribute__((address_space(3))) void*)l, 16, 0, 0);
}

// ---------------- dtype detector (bf16-packed vs fp32 inputs) ----------------
__global__ void k_detect(const unsigned short* __restrict__ raw, int* __restrict__ flag) {
    __shared__ int cnt[4];
    int tid = threadIdx.x;
    int bad = 0;
    for (int i = tid; i < 8192; i += 256) {
        unsigned int u = raw[2 * i];
        float v = __uint_as_float(u << 16);
        if (!(fabsf(v) < 1e6f)) bad++;
    }
#pragma unroll
    for (int o = 32; o > 0; o >>= 1) bad += __shfl_down(bad, o, 64);
    int lane = tid & 63, w = tid >> 6;
    if (lane == 0) cnt[w] = bad;
    __syncthreads();
    if (tid == 0) flag[0] = (cnt[0] + cnt[1] + cnt[2] + cnt[3] < 32) ? 1 : 0;
}

// ---------------- convert 3 weight matrices to bf16, 8 elems/thread ----------------
__global__ __launch_bounds__(256) void k_convert3(const void* __restrict__ s0,
                                                  const void* __restrict__ s1,
                                                  const void* __restrict__ s2,
                                                  bf16* __restrict__ d0,
                                                  bf16* __restrict__ d1,
                                                  bf16* __restrict__ d2,
                                                  const int* __restrict__ flag) {
    const int per = NN * DD / 8;  // 131072 16B-chunks per matrix
    int i = blockIdx.x * 256 + threadIdx.x;
    int m = i / per, j = i % per;
    const void* s = (m == 0) ? s0 : (m == 1) ? s1 : s2;
    bf16* d = (m == 0) ? d0 : (m == 1) ? d1 : d2;
    if (flag[0]) {
        ((uint4*)d)[j] = ((const uint4*)s)[j];  // already bf16: straight copy
    } else {
        const float4* f = (const float4*)s;
        float4 a = f[2 * j], b = f[2 * j + 1];
        short8 o;
        float va[8] = {a.x, a.y, a.z, a.w, b.x, b.y, b.z, b.w};
#pragma unroll
        for (int k = 0; k < 8; k++) {
            bf16 t = __float2bfloat16(va[k]);
            o[k] = *reinterpret_cast<short*>(&t);
        }
        ((short8*)d)[j] = o;
    }
}

// ---------------- gather embeddings: Vp (raw) and U=LN(row), both bf16 ----------------
__global__ __launch_bounds__(256) void k_gather_ln(const void* __restrict__ emb,
                                                   const int* __restrict__ idx,
                                                   bf16* __restrict__ Vpb,
                                                   bf16* __restrict__ Ub,
                                                   const int* __restrict__ flag) {
    __shared__ float s4[4];
    int r = blockIdx.x, d = threadIdx.x;
    int tok = idx[r];
    long o = (long)tok * DD + d;
    float e = flag[0] ? __bfloat162float(((const bf16*)emb)[o]) : ((const float*)emb)[o];
    Vpb[(long)r * DD + d] = __float2bfloat16(e);
    float m = blk_sum_256(e, s4) * (1.0f / DD);
    float zc = e - m;
    float var = blk_sum_256(zc * zc, s4) * (1.0f / (DD - 1));
    Ub[(long)r * DD + d] = __float2bfloat16(zc / (sqrtf(fmaxf(var, 0.f)) + EPS));
}

// ---------------- per-batch transpose Ub[b][t][d] -> Ut[b][d][t] ----------------
__global__ __launch_bounds__(256) void k_transpose(const bf16* __restrict__ Ub,
                                                   bf16* __restrict__ Ut) {
    __shared__ bf16 tile[32][33];
    int b = blockIdx.z;
    int t0 = blockIdx.x * 32, d0 = blockIdx.y * 32;
    const bf16* src = Ub + (long)b * TT * DD;
    bf16* dst = Ut + (long)b * DD * TT;
    int rr = threadIdx.x >> 3, c4 = (threadIdx.x & 7) * 4;
#pragma unroll
    for (int i = 0; i < 4; i++) tile[rr][c4 + i] = src[(long)(t0 + rr) * DD + d0 + c4 + i];
    __syncthreads();
#pragma unroll
    for (int i = 0; i < 4; i++) dst[(long)(d0 + rr) * TT + t0 + c4 + i] = tile[c4 + i][rr];
}

// ---------------- MFMA bf16 NT GEMM: C[m,n] = sum_k A[m,k]*B[n,k] ----------------
// 128x128 tile, BK=32, 4 waves of 4x4 16x16x32 MFMAs.
// v2: double-buffered LDS with prefetch (stage tile t+1 during compute of t,
//     ONE barrier per K-step) + chunk-XOR LDS swizzle via pre-swizzled global
//     source (gl16 dest is forced linear, m104): slot (row,s) holds global
//     chunk c = ((row>>1)&3)^s, so fragment reads spread 8 bank-quads (2-way,
//     free) instead of 8-way conflicts. Stage keeps full 64B/row coalescing.
// bf16-output paths use an LDS-repack epilogue -> coalesced 16B stores.
enum { EPI_RELU_BF16 = 0, EPI_NONE_F32 = 1, EPI_RELU_MULX_BF16 = 2 };

template <int EPI, int KSPLIT, int TRI>
__global__ __launch_bounds__(256) void k_mfma_nt(int K,
                                                 const bf16* __restrict__ A, int lda, long sA,
                                                 const bf16* __restrict__ B, int ldb, long sB,
                                                 void* __restrict__ Cv, int ldc, long sC,
                                                 const bf16* __restrict__ Xaux,
                                                 float* __restrict__ Wsum) {
    __shared__ __align__(16) char smem[32768];  // 2 x (As 8KB | Bs 8KB)
    bf16* R = (bf16*)smem;  // [64][136] repack buffer (overlays buffers, used post-loop)

    int z = blockIdx.z;
    int bz = z / KSPLIT, ks = z % KSPLIT;
    A += (long)bz * sA;
    B += (long)bz * sB;
    int bx = blockIdx.x, by = blockIdx.y;
    if (TRI) {  // 3-tile lower-triangular mapping: 0->(0,0) 1->(0,1) 2->(1,1)
        by = (blockIdx.x >= 1) ? 1 : 0;
        bx = (blockIdx.x == 2) ? 1 : 0;
    }
    int bm = by * 128, bn = bx * 128;
    int tid = threadIdx.x;
    int srow = tid >> 2;
    // pre-swizzled global chunk so linear LDS slot (row, s=tid&3) holds chunk ((row>>1)&3)^s
    int scol = ((((srow >> 1) & 3) ^ (tid & 3)) << 3);
    int w = tid >> 6, lane = tid & 63;
    int wm = (w >> 1) * 64, wn = (w & 1) * 64;
    int lm = lane & 15, kh = lane >> 4;

    floatx4 acc[4][4];
#pragma unroll
    for (int i = 0; i < 4; i++)
#pragma unroll
        for (int j = 0; j < 4; j++) acc[i][j] = (floatx4){0.f, 0.f, 0.f, 0.f};

    int kchunk = K / KSPLIT;
    int kbeg = ks * kchunk, kend = kbeg + kchunk;
    const bf16* gA0 = A + (long)(bm + srow) * lda + scol;
    const bf16* gA1 = gA0 + (long)64 * lda;
    const bf16* gB0 = B + (long)(bn + srow) * ldb + scol;
    const bf16* gB1 = gB0 + (long)64 * ldb;
    // forced-linear LDS dests: lane tid -> byte tid*16 within each 4KB half
    int dslot = tid * 8;  // bf16 elements

    // prologue: stage first tile into buffer 0
    {
        bf16* bufA = (bf16*)smem;
        bf16* bufB = bufA + 4096;
        gl16(gA0 + kbeg, bufA + dslot);
        gl16(gA1 + kbeg, bufA + 2048 + dslot);
        gl16(gB0 + kbeg, bufB + dslot);
        gl16(gB1 + kbeg, bufB + 2048 + dslot);
    }
    __syncthreads();

    int cur = 0;
    for (int k0 = kbeg; k0 < kend; k0 += 32) {
        bf16* cbA = (bf16*)(smem + (cur ? 16384 : 0));
        bf16* cbB = cbA + 4096;
        bf16* nbA = (bf16*)(smem + (cur ? 0 : 16384));
        bf16* nbB = nbA + 4096;
        if (k0 + 32 < kend) {  // prefetch next tile into other buffer (in flight during MFMA)
            gl16(gA0 + k0 + 32, nbA + dslot);
            gl16(gA1 + k0 + 32, nbA + 2048 + dslot);
            gl16(gB0 + k0 + 32, nbB + dslot);
            gl16(gB1 + k0 + 32, nbB + 2048 + dslot);
        }
        short8 af[4], bfr[4];
#pragma unroll
        for (int i = 0; i < 4; i++) {
            int row = wm + i * 16 + lm;
            af[i] = *(const short8*)(cbA + row * 32 + ((((row >> 1) & 3) ^ kh) << 3));
        }
#pragma unroll
        for (int j = 0; j < 4; j++) {
            int row = wn + j * 16 + lm;
            bfr[j] = *(const short8*)(cbB + row * 32 + ((((row >> 1) & 3) ^ kh) << 3));
        }
#pragma unroll
        for (int i = 0; i < 4; i++)
#pragma unroll
            for (int j = 0; j < 4; j++)
                acc[i][j] = __builtin_amdgcn_mfma_f32_16x16x32_bf16(af[i], bfr[j], acc[i][j], 0, 0, 0);
        __syncthreads();  // drains next-tile vmcnt + our ds_reads; ONE barrier per K-step
        cur ^= 1;
    }

    if (EPI == EPI_NONE_F32) {
        long cbase = (long)z * sC;
#pragma unroll
        for (int i = 0; i < 4; i++)
#pragma unroll
            for (int j = 0; j < 4; j++)
#pragma unroll
                for (int r = 0; r < 4; r++) {
                    int gm = bm + wm + i * 16 + kh * 4 + r;
                    int gn = bn + wn + j * 16 + lm;
                    ((float*)Cv)[cbase + (long)gm * ldc + gn] = acc[i][j][r];
                }
        return;
    }

    // ---- LDS-repack epilogue: two 64-row passes, coalesced 16B stores ----
#pragma unroll
    for (int p = 0; p < 2; p++) {
        __syncthreads();
        if ((w >> 1) == p) {
#pragma unroll
            for (int i = 0; i < 4; i++)
#pragma unroll
                for (int j = 0; j < 4; j++)
#pragma unroll
                    for (int r = 0; r < 4; r++) {
                        int rr = i * 16 + kh * 4 + r;
                        int cc = wn + j * 16 + lm;
                        R[rr * 136 + cc] = __float2bfloat16(fmaxf(acc[i][j][r], 0.f));
                    }
        }
        __syncthreads();
#pragma unroll
        for (int it = 0; it < 4; it++) {
            int row_l = it * 16 + (tid >> 4);
            int c8 = (tid & 15) * 8;
            short8 vv = *(const short8*)(R + row_l * 136 + c8);
            int gm = bm + p * 64 + row_l;
            long off = (long)gm * ldc + bn + c8;
            if (EPI == EPI_RELU_BF16) {
                *(short8*)((bf16*)Cv + off) = vv;
                float s = 0.f;
#pragma unroll
                for (int k = 0; k < 8; k++) s += bfu2f(vv[k]);
#pragma unroll
                for (int o = 8; o > 0; o >>= 1) s += __shfl_down(s, o, 16);
                if ((tid & 15) == 0) atomicAdd(&Wsum[gm], s);
            } else {  // EPI_RELU_MULX_BF16
                short8 xx = *(const short8*)(Xaux + off);
                short8 oo;
#pragma unroll
                for (int k = 0; k < 8; k++) {
                    float prod = bfu2f(vv[k]) * fmaxf(bfu2f(xx[k]), 0.f);
                    bf16 t = __float2bfloat16(prod);
                    oo[k] = *reinterpret_cast<short*>(&t);
                }
                *(short8*)((bf16*)Cv + off) = oo;
            }
        }
    }
}

// ---------------- scalar normalizer recurrence ----------------
// S_t = 0.97 * S_{t-1}/(S_{t-1}+eps) + W_t ; invS[t] = 1/(S_t+eps)
__global__ __launch_bounds__(256) void k_scalar_scan(const float* __restrict__ Wsum,
                                                     float* __restrict__ invS) {
    __shared__ float sw[BB * TT];
    for (int i = threadIdx.x; i < BB * TT; i += 256) sw[i] = Wsum[i];
    __syncthreads();
    int b = threadIdx.x;
    if (b < BB) {
        float sig = 0.f;
        for (int t = 0; t < TT; t++) {
            float S = DECAY * sig + sw[b * TT + t];
            float inv = 1.f / (S + EPS);
            invS[b * TT + t] = inv;
            sig = S * inv;
        }
    }
}

// ---------------- barrier-free column scan: x = (0.97 x + w) * invS[t] ----------------
__global__ __launch_bounds__(256) void k_colscan(bf16* __restrict__ W,
                                                 const float* __restrict__ invS) {
    __shared__ float sv[TT];
    int b = blockIdx.y;
    sv[threadIdx.x] = invS[b * TT + threadIdx.x];
    __syncthreads();
    int n = blockIdx.x * 256 + threadIdx.x;
    bf16* p = W + (long)b * TT * NN + n;
    float x = 0.f;
    for (int t = 0; t < TT; t++) {
        float w = __bfloat162float(p[(long)t * NN]);
        x = (DECAY * x + w) * sv[t];
        p[(long)t * NN] = __float2bfloat16(x);
    }
}

// ---------------- reduce 4 split-K score partials + causal decay mask -> G bf16 ----------------
__global__ __launch_bounds__(256) void k_reduce_mask(const float* __restrict__ Gp,
                                                     bf16* __restrict__ G) {
    int r = blockIdx.x;
    int b = r >> 8, t = r & 255;
    int s = threadIdx.x;
    long base = ((long)b * 4) * 65536 + (long)t * 256 + s;
    float v = Gp[base] + Gp[base + 65536] + Gp[base + 2 * 65536] + Gp[base + 3 * 65536];
    float o = (s < t) ? v * exp2f((float)(t - s) * LOG2_DECAY) : 0.f;
    G[(long)r * 256 + s] = __float2bfloat16(o);
}

// ---------------- sum 2 attn split-K partials + row layernorm -> ALN bf16 ----------------
__global__ __launch_bounds__(256) void k_ln_rows(const float* __restrict__ Zp,
                                                 bf16* __restrict__ O) {
    __shared__ float s4[4];
    long r = blockIdx.x;
    int d = threadIdx.x;
    long b = r >> 8, t = r & 255;
    long base = (b * 2) * 65536 + t * 256 + d;
    float z = Zp[base] + Zp[base + 65536];
    float m = blk_sum_256(z, s4) * (1.0f / DD);
    float zc = z - m;
    float var = blk_sum_256(zc * zc, s4) * (1.0f / (DD - 1));
    O[r * DD + d] = __float2bfloat16(zc / (sqrtf(fmaxf(var, 0.f)) + EPS));
}

// ---------------- sum 4 split-K Z partials + layernorm -> output ----------------
__global__ __launch_bounds__(256) void k_final_ln(const float* __restrict__ Zp,
                                                  void* __restrict__ out,
                                                  const int* __restrict__ flag) {
    __shared__ float s4[4];
    long r = blockIdx.x;
    int d = threadIdx.x;
    const long SL = (long)8192 * 256;
    long o = r * DD + d;
    float z = Zp[o] + Zp[o + SL] + Zp[o + 2 * SL] + Zp[o + 3 * SL];
    float m = blk_sum_256(z, s4) * (1.0f / DD);
    float zc = z - m;
    float var = blk_sum_256(zc * zc, s4) * (1.0f / (DD - 1));
    float v = zc / (sqrtf(fmaxf(var, 0.f)) + EPS);
    if (flag[0]) ((bf16*)out)[o] = __float2bfloat16(v);
    else ((float*)out)[o] = v;
}

extern "C" void kernel_launch(void* const* d_in, const int* in_sizes, int n_in,
                              void* d_out, int out_size, void* d_ws, size_t ws_size,
                              hipStream_t stream) {
    const int* idx = (const int*)d_in[0];
    const void* emb = d_in[1];
    const void* E = d_in[2];
    const void* Dx = d_in[3];
    const void* Dy = d_in[4];

    // ---- workspace carve (bytes) ----
    char* base = (char*)d_ws;
    size_t off = 0;
    int* flag = (int*)base; off += 1024;
    bf16* Dxb = (bf16*)(base + off); off += (size_t)NN * DD * 2;
    bf16* Dyb = (bf16*)(base + off); off += (size_t)NN * DD * 2;
    bf16* Eb  = (bf16*)(base + off); off += (size_t)DD * NN * 2;
    bf16* Vpb = (bf16*)(base + off); off += (size_t)BB * TT * DD * 2;
    bf16* Ub  = (bf16*)(base + off); off += (size_t)BB * TT * DD * 2;
    bf16* Ut  = (bf16*)(base + off); off += (size_t)BB * TT * DD * 2;
    float* Wsum = (float*)(base + off); off += (size_t)BB * TT * 4;
    float* invS = (float*)(base + off); off += (size_t)BB * TT * 4;
    bf16* ALNb = (bf16*)(base + off); off += (size_t)BB * TT * DD * 2;
    bf16* G = (bf16*)(base + off); off += (size_t)BB * TT * TT * 2;
    float* Gp = (float*)(base + off); off += (size_t)4 * BB * TT * TT * 4;  // 33.5MB
    float* Astar = Gp;  // attn partials alias Gp (free after reduce_mask)
    float* Zp = Gp;     // Z partials alias Gp (free after ln_rows)
    bf16* Xb = (bf16*)(base + off); off += (size_t)BB * TT * NN * 2;        // 67MB

    const int M = BB * TT;  // 8192

    k_detect<<<1, 256, 0, stream>>>((const unsigned short*)emb, flag);
    k_convert3<<<3 * NN * DD / 8 / 256, 256, 0, stream>>>(Dx, Dy, E, Dxb, Dyb, Eb, flag);
    k_gather_ln<<<M, 256, 0, stream>>>(emb, idx, Vpb, Ub, flag);
    k_transpose<<<dim3(8, 8, BB), 256, 0, stream>>>(Ub, Ut);

    hipMemsetAsync(Wsum, 0, (size_t)M * 4, stream);

    // W = relu(Vp @ Dx^T) -> Xb (bf16), rowsums fused via atomics
    k_mfma_nt<EPI_RELU_BF16, 1, 0><<<dim3(32, 64, 1), 256, 0, stream>>>(
        DD, Vpb, DD, 0, Dxb, DD, 0, Xb, NN, 0, nullptr, Wsum);

    k_scalar_scan<<<1, 256, 0, stream>>>(Wsum, invS);
    k_colscan<<<dim3(16, BB, 1), 256, 0, stream>>>(Xb, invS);

    // scores partials: 3 lower-triangular tiles only, split-K 4
    k_mfma_nt<EPI_NONE_F32, 4, 1><<<dim3(3, 1, BB * 4), 256, 0, stream>>>(
        NN, Xb, NN, (long)TT * NN, Xb, NN, (long)TT * NN, Gp, TT, (long)TT * TT, nullptr, nullptr);
    k_reduce_mask<<<M, 256, 0, stream>>>(Gp, G);

    // a* partials = Gm @ U (NT with Ut), batched, split-K 2 (alias into Gp region)
    k_mfma_nt<EPI_NONE_F32, 2, 0><<<dim3(2, 2, BB * 2), 256, 0, stream>>>(
        TT, G, TT, (long)TT * TT, Ut, TT, (long)DD * TT, Astar, DD, (long)TT * DD, nullptr, nullptr);
    k_ln_rows<<<M, 256, 0, stream>>>(Astar, ALNb);

    // Y = relu(ALN @ Dy^T) * relu(X), in place over Xb
    k_mfma_nt<EPI_RELU_MULX_BF16, 1, 0><<<dim3(32, 64, 1), 256, 0, stream>>>(
        DD, ALNb, DD, 0, Dyb, DD, 0, Xb, NN, 0, Xb, nullptr);

    // Z partials = Y @ E^T (split-K 4)
    k_mfma_nt<EPI_NONE_F32, 4, 0><<<dim3(2, 64, 4), 256, 0, stream>>>(
        NN, Xb, NN, 0, Eb, NN, 0, Zp, DD, (long)M * DD, nullptr, nullptr);

    k_final_ln<<<M, 256, 0, stream>>>(Zp, d_out, flag);
}

// Round 2
// 310.195 us; speedup vs baseline: 1.0901x; 1.0297x over previous
//
#include <hip/hip_runtime.h>
#include <hip/hip_bf16.h>

#define NN 4096
#define DD 256
#define BB 32
#define TT 256
#define EPS 1e-6f
#define DECAY 0.97f
#define LOG2_DECAY -0.043943348f

typedef __hip_bfloat16 bf16;
typedef short short8 __attribute__((ext_vector_type(8)));
typedef float floatx4 __attribute__((ext_vector_type(4)));

__device__ __forceinline__ float bfu2f(short u) {
    return __uint_as_float(((unsigned)(unsigned short)u) << 16);
}

// ---------------- block-wide sum over 256 threads ----------------
__device__ __forceinline__ float blk_sum_256(float v, volatile float* s4) {
#pragma unroll
    for (int o = 32; o > 0; o >>= 1) v += __shfl_down(v, o, 64);
    int lane = threadIdx.x & 63, w = threadIdx.x >> 6;
    __syncthreads();
    if (lane == 0) s4[w] = v;
    __syncthreads();
    return s4[0] + s4[1] + s4[2] + s4[3];
}

// async global->LDS, 16B per lane; LDS dest must be wave-uniform base + lane*16
__device__ __forceinline__ void gl16(const bf16* g, bf16* l) {
    __builtin_amdgcn_global_load_lds((const __attribute__((address_space(1))) void*)g,
                                     (__attribute__((address_space(3))) void*)l, 16, 0, 0);
}

// ---------------- dtype detector (bf16-packed vs fp32 inputs) ----------------
__global__ void k_detect(const unsigned short* __restrict__ raw, int* __restrict__ flag) {
    __shared__ int cnt[4];
    int tid = threadIdx.x;
    int bad = 0;
    for (int i = tid; i < 8192; i += 256) {
        unsigned int u = raw[2 * i];
        float v = __uint_as_float(u << 16);
        if (!(fabsf(v) < 1e6f)) bad++;
    }
#pragma unroll
    for (int o = 32; o > 0; o >>= 1) bad += __shfl_down(bad, o, 64);
    int lane = tid & 63, w = tid >> 6;
    if (lane == 0) cnt[w] = bad;
    __syncthreads();
    if (tid == 0) flag[0] = (cnt[0] + cnt[1] + cnt[2] + cnt[3] < 32) ? 1 : 0;
}

// ---------------- convert 3 weight matrices to bf16, 8 elems/thread ----------------
__global__ __launch_bounds__(256) void k_convert3(const void* __restrict__ s0,
                                                  const void* __restrict__ s1,
                                                  const void* __restrict__ s2,
                                                  bf16* __restrict__ d0,
                                                  bf16* __restrict__ d1,
                                                  bf16* __restrict__ d2,
                                                  const int* __restrict__ flag) {
    const int per = NN * DD / 8;  // 131072 16B-chunks per matrix
    int i = blockIdx.x * 256 + threadIdx.x;
    int m = i / per, j = i % per;
    const void* s = (m == 0) ? s0 : (m == 1) ? s1 : s2;
    bf16* d = (m == 0) ? d0 : (m == 1) ? d1 : d2;
    if (flag[0]) {
        ((uint4*)d)[j] = ((const uint4*)s)[j];  // already bf16: straight copy
    } else {
        const float4* f = (const float4*)s;
        float4 a = f[2 * j], b = f[2 * j + 1];
        short8 o;
        float va[8] = {a.x, a.y, a.z, a.w, b.x, b.y, b.z, b.w};
#pragma unroll
        for (int k = 0; k < 8; k++) {
            bf16 t = __float2bfloat16(va[k]);
            o[k] = *reinterpret_cast<short*>(&t);
        }
        ((short8*)d)[j] = o;
    }
}

// ---------------- gather embeddings: Vp (raw) and U=LN(row), both bf16 ----------------
__global__ __launch_bounds__(256) void k_gather_ln(const void* __restrict__ emb,
                                                   const int* __restrict__ idx,
                                                   bf16* __restrict__ Vpb,
                                                   bf16* __restrict__ Ub,
                                                   const int* __restrict__ flag) {
    __shared__ float s4[4];
    int r = blockIdx.x, d = threadIdx.x;
    int tok = idx[r];
    long o = (long)tok * DD + d;
    float e = flag[0] ? __bfloat162float(((const bf16*)emb)[o]) : ((const float*)emb)[o];
    Vpb[(long)r * DD + d] = __float2bfloat16(e);
    float m = blk_sum_256(e, s4) * (1.0f / DD);
    float zc = e - m;
    float var = blk_sum_256(zc * zc, s4) * (1.0f / (DD - 1));
    Ub[(long)r * DD + d] = __float2bfloat16(zc / (sqrtf(fmaxf(var, 0.f)) + EPS));
}

// ---------------- per-batch transpose Ub[b][t][d] -> Ut[b][d][t] ----------------
__global__ __launch_bounds__(256) void k_transpose(const bf16* __restrict__ Ub,
                                                   bf16* __restrict__ Ut) {
    __shared__ bf16 tile[32][33];
    int b = blockIdx.z;
    int t0 = blockIdx.x * 32, d0 = blockIdx.y * 32;
    const bf16* src = Ub + (long)b * TT * DD;
    bf16* dst = Ut + (long)b * DD * TT;
    int rr = threadIdx.x >> 3, c4 = (threadIdx.x & 7) * 4;
#pragma unroll
    for (int i = 0; i < 4; i++) tile[rr][c4 + i] = src[(long)(t0 + rr) * DD + d0 + c4 + i];
    __syncthreads();
#pragma unroll
    for (int i = 0; i < 4; i++) dst[(long)(d0 + rr) * TT + t0 + c4 + i] = tile[c4 + i][rr];
}

// ---------------- MFMA bf16 NT GEMM: C[m,n] = sum_k A[m,k]*B[n,k] ----------------
// 128x128 tile, BK=32, 4 waves of 4x4 16x16x32 MFMAs.
// v3: TRIPLE-buffered LDS, prefetch distance 2, counted s_waitcnt vmcnt(8/4/0)
//     with raw s_barrier (T3+T4: never drain vmcnt to 0 mid-loop; __syncthreads
//     would force vmcnt(0) each step). Chunk-XOR LDS swizzle via pre-swizzled
//     global source (gl16 dest forced linear). Bijective XCD swizzle (SWZ)
//     keeps consecutive row-panels on one XCD's L2.
// bf16-output paths use an LDS-repack epilogue -> coalesced 16B stores.
enum { EPI_RELU_BF16 = 0, EPI_NONE_F32 = 1, EPI_RELU_MULX_BF16 = 2 };

template <int EPI, int KSPLIT, int TRI, int SWZ>
__global__ __launch_bounds__(256) void k_mfma_nt(int K,
                                                 const bf16* __restrict__ A, int lda, long sA,
                                                 const bf16* __restrict__ B, int ldb, long sB,
                                                 void* __restrict__ Cv, int ldc, long sC,
                                                 const bf16* __restrict__ Xaux,
                                                 float* __restrict__ Wsum) {
    __shared__ __align__(16) char smem[49152];  // 3 x (As 8KB | Bs 8KB)
    bf16* R = (bf16*)smem;  // [64][136] repack buffer (overlays buffers, used post-loop)

    int z = blockIdx.z;
    int bz = z / KSPLIT, ks = z % KSPLIT;
    A += (long)bz * sA;
    B += (long)bz * sB;
    int bx = blockIdx.x, by = blockIdx.y;
    if (TRI) {  // 3-tile lower-triangular mapping: 0->(0,0) 1->(0,1) 2->(1,1)
        by = (blockIdx.x >= 1) ? 1 : 0;
        bx = (blockIdx.x == 2) ? 1 : 0;
    }
    if (SWZ) {  // bijective XCD swizzle over the xy-plane (requires nwg%8==0)
        int gx = gridDim.x;
        int nwg = gx * gridDim.y;
        int id = by * gx + bx;
        int q = nwg >> 3;
        int nid = (id & 7) * q + (id >> 3);
        bx = nid % gx;
        by = nid / gx;
    }
    int bm = by * 128, bn = bx * 128;
    int tid = threadIdx.x;
    int srow = tid >> 2;
    // pre-swizzled global chunk so linear LDS slot (row, s=tid&3) holds chunk ((row>>1)&3)^s
    int scol = ((((srow >> 1) & 3) ^ (tid & 3)) << 3);
    int w = tid >> 6, lane = tid & 63;
    int wm = (w >> 1) * 64, wn = (w & 1) * 64;
    int lm = lane & 15, kh = lane >> 4;

    floatx4 acc[4][4];
#pragma unroll
    for (int i = 0; i < 4; i++)
#pragma unroll
        for (int j = 0; j < 4; j++) acc[i][j] = (floatx4){0.f, 0.f, 0.f, 0.f};

    int kchunk = K / KSPLIT;
    int kbeg = ks * kchunk, kend = kbeg + kchunk;
    const bf16* gA0 = A + (long)(bm + srow) * lda + scol;
    const bf16* gA1 = gA0 + (long)64 * lda;
    const bf16* gB0 = B + (long)(bn + srow) * ldb + scol;
    const bf16* gB1 = gB0 + (long)64 * ldb;
    // forced-linear LDS dests: lane tid -> byte tid*16 within each 4KB half
    int dslot = tid * 8;  // bf16 elements

#define STAGE_SLOT(SBASE, KK)                          \
    {                                                  \
        bf16* bufA = (bf16*)(SBASE);                   \
        bf16* bufB = bufA + 4096;                      \
        gl16(gA0 + (KK), bufA + dslot);                \
        gl16(gA1 + (KK), bufA + 2048 + dslot);         \
        gl16(gB0 + (KK), bufB + dslot);                \
        gl16(gB1 + (KK), bufB + 2048 + dslot);         \
    }

    // prologue: prefetch distance 2
    STAGE_SLOT(smem, kbeg);
    if (kbeg + 32 < kend) STAGE_SLOT(smem + 16384, kbeg + 32);

    int cur = 0;
    for (int k0 = kbeg; k0 < kend; k0 += 32) {
        __builtin_amdgcn_s_barrier();  // prev compute done everywhere -> safe to overwrite slot cur+2
        __builtin_amdgcn_sched_barrier(0);
        if (k0 + 64 < kend) {
            int ps = (cur == 0) ? 2 : cur - 1;  // (cur+2)%3
            STAGE_SLOT(smem + ps * 16384, k0 + 64);
        }
        int rem = (kend - k0 - 32) >> 5;  // stages still in flight beyond current
        if (rem >= 2)      asm volatile("s_waitcnt vmcnt(8)" ::: "memory");
        else if (rem == 1) asm volatile("s_waitcnt vmcnt(4)" ::: "memory");
        else               asm volatile("s_waitcnt vmcnt(0)" ::: "memory");
        __builtin_amdgcn_s_barrier();  // all waves' stage-(t) writes landed -> slot cur full
        __builtin_amdgcn_sched_barrier(0);
        bf16* cbA = (bf16*)(smem + cur * 16384);
        bf16* cbB = cbA + 4096;
        short8 af[4], bfr[4];
#pragma unroll
        for (int i = 0; i < 4; i++) {
            int row = wm + i * 16 + lm;
            af[i] = *(const short8*)(cbA + row * 32 + ((((row >> 1) & 3) ^ kh) << 3));
        }
#pragma unroll
        for (int j = 0; j < 4; j++) {
            int row = wn + j * 16 + lm;
            bfr[j] = *(const short8*)(cbB + row * 32 + ((((row >> 1) & 3) ^ kh) << 3));
        }
#pragma unroll
        for (int i = 0; i < 4; i++)
#pragma unroll
            for (int j = 0; j < 4; j++)
                acc[i][j] = __builtin_amdgcn_mfma_f32_16x16x32_bf16(af[i], bfr[j], acc[i][j], 0, 0, 0);
        cur = (cur == 2) ? 0 : cur + 1;
    }
#undef STAGE_SLOT

    if (EPI == EPI_NONE_F32) {
        long cbase = (long)z * sC;
#pragma unroll
        for (int i = 0; i < 4; i++)
#pragma unroll
            for (int j = 0; j < 4; j++)
#pragma unroll
                for (int r = 0; r < 4; r++) {
                    int gm = bm + wm + i * 16 + kh * 4 + r;
                    int gn = bn + wn + j * 16 + lm;
                    ((float*)Cv)[cbase + (long)gm * ldc + gn] = acc[i][j][r];
                }
        return;
    }

    // ---- LDS-repack epilogue: two 64-row passes, coalesced 16B stores ----
#pragma unroll
    for (int p = 0; p < 2; p++) {
        __syncthreads();
        if ((w >> 1) == p) {
#pragma unroll
            for (int i = 0; i < 4; i++)
#pragma unroll
                for (int j = 0; j < 4; j++)
#pragma unroll
                    for (int r = 0; r < 4; r++) {
                        int rr = i * 16 + kh * 4 + r;
                        int cc = wn + j * 16 + lm;
                        R[rr * 136 + cc] = __float2bfloat16(fmaxf(acc[i][j][r], 0.f));
                    }
        }
        __syncthreads();
#pragma unroll
        for (int it = 0; it < 4; it++) {
            int row_l = it * 16 + (tid >> 4);
            int c8 = (tid & 15) * 8;
            short8 vv = *(const short8*)(R + row_l * 136 + c8);
            int gm = bm + p * 64 + row_l;
            long off = (long)gm * ldc + bn + c8;
            if (EPI == EPI_RELU_BF16) {
                *(short8*)((bf16*)Cv + off) = vv;
                float s = 0.f;
#pragma unroll
                for (int k = 0; k < 8; k++) s += bfu2f(vv[k]);
#pragma unroll
                for (int o = 8; o > 0; o >>= 1) s += __shfl_down(s, o, 16);
                if ((tid & 15) == 0) atomicAdd(&Wsum[gm], s);
            } else {  // EPI_RELU_MULX_BF16
                short8 xx = *(const short8*)(Xaux + off);
                short8 oo;
#pragma unroll
                for (int k = 0; k < 8; k++) {
                    float prod = bfu2f(vv[k]) * fmaxf(bfu2f(xx[k]), 0.f);
                    bf16 t = __float2bfloat16(prod);
                    oo[k] = *reinterpret_cast<short*>(&t);
                }
                *(short8*)((bf16*)Cv + off) = oo;
            }
        }
    }
}

// ---------------- scalar normalizer recurrence ----------------
// S_t = 0.97 * S_{t-1}/(S_{t-1}+eps) + W_t ; invS[t] = 1/(S_t+eps)
__global__ __launch_bounds__(256) void k_scalar_scan(const float* __restrict__ Wsum,
                                                     float* __restrict__ invS) {
    __shared__ float sw[BB * TT];
    for (int i = threadIdx.x; i < BB * TT; i += 256) sw[i] = Wsum[i];
    __syncthreads();
    int b = threadIdx.x;
    if (b < BB) {
        float sig = 0.f;
        for (int t = 0; t < TT; t++) {
            float S = DECAY * sig + sw[b * TT + t];
            float inv = 1.f / (S + EPS);
            invS[b * TT + t] = inv;
            sig = S * inv;
        }
    }
}

// ---------------- barrier-free column scan: x = (0.97 x + w) * invS[t] ----------------
__global__ __launch_bounds__(256) void k_colscan(bf16* __restrict__ W,
                                                 const float* __restrict__ invS) {
    __shared__ float sv[TT];
    int b = blockIdx.y;
    sv[threadIdx.x] = invS[b * TT + threadIdx.x];
    __syncthreads();
    int n = blockIdx.x * 256 + threadIdx.x;
    bf16* p = W + (long)b * TT * NN + n;
    float x = 0.f;
    for (int t = 0; t < TT; t++) {
        float w = __bfloat162float(p[(long)t * NN]);
        x = (DECAY * x + w) * sv[t];
        p[(long)t * NN] = __float2bfloat16(x);
    }
}

// ---------------- reduce 4 split-K score partials + causal decay mask -> G bf16 ----------------
__global__ __launch_bounds__(256) void k_reduce_mask(const float* __restrict__ Gp,
                                                     bf16* __restrict__ G) {
    int r = blockIdx.x;
    int b = r >> 8, t = r & 255;
    int s = threadIdx.x;
    long base = ((long)b * 4) * 65536 + (long)t * 256 + s;
    float v = Gp[base] + Gp[base + 65536] + Gp[base + 2 * 65536] + Gp[base + 3 * 65536];
    float o = (s < t) ? v * exp2f((float)(t - s) * LOG2_DECAY) : 0.f;
    G[(long)r * 256 + s] = __float2bfloat16(o);
}

// ---------------- sum 2 attn split-K partials + row layernorm -> ALN bf16 ----------------
__global__ __launch_bounds__(256) void k_ln_rows(const float* __restrict__ Zp,
                                                 bf16* __restrict__ O) {
    __shared__ float s4[4];
    long r = blockIdx.x;
    int d = threadIdx.x;
    long b = r >> 8, t = r & 255;
    long base = (b * 2) * 65536 + t * 256 + d;
    float z = Zp[base] + Zp[base + 65536];
    float m = blk_sum_256(z, s4) * (1.0f / DD);
    float zc = z - m;
    float var = blk_sum_256(zc * zc, s4) * (1.0f / (DD - 1));
    O[r * DD + d] = __float2bfloat16(zc / (sqrtf(fmaxf(var, 0.f)) + EPS));
}

// ---------------- sum 4 split-K Z partials + layernorm -> output ----------------
__global__ __launch_bounds__(256) void k_final_ln(const float* __restrict__ Zp,
                                                  void* __restrict__ out,
                                                  const int* __restrict__ flag) {
    __shared__ float s4[4];
    long r = blockIdx.x;
    int d = threadIdx.x;
    const long SL = (long)8192 * 256;
    long o = r * DD + d;
    float z = Zp[o] + Zp[o + SL] + Zp[o + 2 * SL] + Zp[o + 3 * SL];
    float m = blk_sum_256(z, s4) * (1.0f / DD);
    float zc = z - m;
    float var = blk_sum_256(zc * zc, s4) * (1.0f / (DD - 1));
    float v = zc / (sqrtf(fmaxf(var, 0.f)) + EPS);
    if (flag[0]) ((bf16*)out)[o] = __float2bfloat16(v);
    else ((float*)out)[o] = v;
}

extern "C" void kernel_launch(void* const* d_in, const int* in_sizes, int n_in,
                              void* d_out, int out_size, void* d_ws, size_t ws_size,
                              hipStream_t stream) {
    const int* idx = (const int*)d_in[0];
    const void* emb = d_in[1];
    const void* E = d_in[2];
    const void* Dx = d_in[3];
    const void* Dy = d_in[4];

    // ---- workspace carve (bytes) ----
    char* base = (char*)d_ws;
    size_t off = 0;
    int* flag = (int*)base; off += 1024;
    bf16* Dxb = (bf16*)(base + off); off += (size_t)NN * DD * 2;
    bf16* Dyb = (bf16*)(base + off); off += (size_t)NN * DD * 2;
    bf16* Eb  = (bf16*)(base + off); off += (size_t)DD * NN * 2;
    bf16* Vpb = (bf16*)(base + off); off += (size_t)BB * TT * DD * 2;
    bf16* Ub  = (bf16*)(base + off); off += (size_t)BB * TT * DD * 2;
    bf16* Ut  = (bf16*)(base + off); off += (size_t)BB * TT * DD * 2;
    float* Wsum = (float*)(base + off); off += (size_t)BB * TT * 4;
    float* invS = (float*)(base + off); off += (size_t)BB * TT * 4;
    bf16* ALNb = (bf16*)(base + off); off += (size_t)BB * TT * DD * 2;
    bf16* G = (bf16*)(base + off); off += (size_t)BB * TT * TT * 2;
    float* Gp = (float*)(base + off); off += (size_t)4 * BB * TT * TT * 4;  // 33.5MB
    float* Astar = Gp;  // attn partials alias Gp (free after reduce_mask)
    float* Zp = Gp;     // Z partials alias Gp (free after ln_rows)
    bf16* Xb = (bf16*)(base + off); off += (size_t)BB * TT * NN * 2;        // 67MB

    const int M = BB * TT;  // 8192

    k_detect<<<1, 256, 0, stream>>>((const unsigned short*)emb, flag);
    k_convert3<<<3 * NN * DD / 8 / 256, 256, 0, stream>>>(Dx, Dy, E, Dxb, Dyb, Eb, flag);
    k_gather_ln<<<M, 256, 0, stream>>>(emb, idx, Vpb, Ub, flag);
    k_transpose<<<dim3(8, 8, BB), 256, 0, stream>>>(Ub, Ut);

    hipMemsetAsync(Wsum, 0, (size_t)M * 4, stream);

    // W = relu(Vp @ Dx^T) -> Xb (bf16), rowsums fused via atomics
    k_mfma_nt<EPI_RELU_BF16, 1, 0, 1><<<dim3(32, 64, 1), 256, 0, stream>>>(
        DD, Vpb, DD, 0, Dxb, DD, 0, Xb, NN, 0, nullptr, Wsum);

    k_scalar_scan<<<1, 256, 0, stream>>>(Wsum, invS);
    k_colscan<<<dim3(16, BB, 1), 256, 0, stream>>>(Xb, invS);

    // scores partials: 3 lower-triangular tiles only, split-K 4
    k_mfma_nt<EPI_NONE_F32, 4, 1, 0><<<dim3(3, 1, BB * 4), 256, 0, stream>>>(
        NN, Xb, NN, (long)TT * NN, Xb, NN, (long)TT * NN, Gp, TT, (long)TT * TT, nullptr, nullptr);
    k_reduce_mask<<<M, 256, 0, stream>>>(Gp, G);

    // a* partials = Gm @ U (NT with Ut), batched, split-K 2 (alias into Gp region)
    k_mfma_nt<EPI_NONE_F32, 2, 0, 0><<<dim3(2, 2, BB * 2), 256, 0, stream>>>(
        TT, G, TT, (long)TT * TT, Ut, TT, (long)DD * TT, Astar, DD, (long)TT * DD, nullptr, nullptr);
    k_ln_rows<<<M, 256, 0, stream>>>(Astar, ALNb);

    // Y = relu(ALN @ Dy^T) * relu(X), in place over Xb
    k_mfma_nt<EPI_RELU_MULX_BF16, 1, 0, 1><<<dim3(32, 64, 1), 256, 0, stream>>>(
        DD, ALNb, DD, 0, Dyb, DD, 0, Xb, NN, 0, Xb, nullptr);

    // Z partials = Y @ E^T (split-K 4)
    k_mfma_nt<EPI_NONE_F32, 4, 0, 1><<<dim3(2, 64, 4), 256, 0, stream>>>(
        NN, Xb, NN, 0, Eb, NN, 0, Zp, DD, (long)M * DD, nullptr, nullptr);

    k_final_ln<<<M, 256, 0, stream>>>(Zp, d_out, flag);
}